// Round 3
// baseline (219.853 us; speedup 1.0000x reference)
//
#include <hip/hip_runtime.h>

// AdderNet 2D: out[n,f,i,j] = -sum_{c,ki,kj} |W[f,c,ki,kj] - xpad[n,c,i+ki,j+kj]|
// x: [8,64,32,32] f32, W: [64,64,3,3] f32, out: [8,64,32,32] f32
//
// R3: LDS-pipe was the binding resource (D=171 cyc/cc vs V/4=36). Now each
// thread computes 8 px (2 rows x 4 cols) x 4 filters, x read as aligned
// b128+b64 per row, W as float4 from padded LDS -> D=195 vs V/4=288:
// VALU-bound. 128-thread blocks, 8 channels/block in 2 staged chunks,
// split-C=8 combined via fp32 atomicAdd on memset-zeroed out.

#define FPB     4
#define CCHUNK  4
#define NCHUNK  2              // channels/block = CCHUNK*NCHUNK = 8
#define SPLITC  8
#define XSTRIDE 36             // LDS row stride (floats), 16B-aligned
#define XROWS   34             // image rows -1..32
#define XCH     (XROWS * XSTRIDE)   // 1224 floats per channel
#define WPAD    12

__global__ __launch_bounds__(128, 2)
void adder2d_kernel(const float* __restrict__ x,
                    const float* __restrict__ Wt,
                    float* __restrict__ out) {
    __shared__ float xs[CCHUNK * XCH];          // 19584 B
    __shared__ float ws[FPB * CCHUNK * WPAD];   //   768 B

    const int bid = blockIdx.x;
    const int ks  = bid & 7;          // channel slice
    const int fg  = (bid >> 3) & 15;  // filter group (fastest after ks -> x reuse)
    const int n   = bid >> 7;         // image
    const int f0  = fg * FPB;
    const int tid = threadIdx.x;

    const int tx = tid & 7;           // col group: cols 4tx..4tx+3
    const int ty = tid >> 3;          // row pair:  rows 2ty..2ty+1

    float acc[2][4][FPB];
#pragma unroll
    for (int rr = 0; rr < 2; ++rr)
#pragma unroll
        for (int c = 0; c < 4; ++c)
#pragma unroll
            for (int f = 0; f < FPB; ++f) acc[rr][c][f] = 0.0f;

    const float* xn = x + ((size_t)n * 64 + ks * (CCHUNK * NCHUNK)) * 1024;
    const float* wn = Wt + ((size_t)f0 * 64 + ks * (CCHUNK * NCHUNK)) * 9;

    for (int ch = 0; ch < NCHUNK; ++ch) {
        // ---- stage W chunk: ws[(f*CCHUNK+cc)*12 + k] ----
        for (int idx = tid; idx < FPB * CCHUNK * 9; idx += 128) {
            const int f   = idx / (CCHUNK * 9);
            const int rem = idx - f * (CCHUNK * 9);
            const int cc  = rem / 9;
            const int kk  = rem - cc * 9;
            ws[(f * CCHUNK + cc) * WPAD + kk] =
                wn[((size_t)f * 64 + ch * CCHUNK + cc) * 9 + kk];
        }
        // ---- stage x chunk: rows -1..32 -> 0..33, col -1 -> index 0 ----
        const float* xc = xn + (size_t)ch * CCHUNK * 1024;
        for (int idx = tid; idx < CCHUNK * XCH; idx += 128) {
            const int cc  = idx / XCH;
            const int rem = idx - cc * XCH;
            const int row = rem / XSTRIDE;          // 0..33 -> global row-1
            const int col = rem - row * XSTRIDE;    // 0..35 -> global col-1
            const int ir  = row - 1;
            const int ic  = col - 1;
            float v = 0.0f;
            if ((unsigned)ir < 32u && (unsigned)ic < 32u)
                v = xc[cc * 1024 + ir * 32 + ic];
            xs[idx] = v;
        }
        __syncthreads();

#pragma unroll
        for (int cc = 0; cc < CCHUNK; ++cc) {
            // x window: LDS rows 2ty..2ty+3, col indices 4tx..4tx+5
            float xr[4][6];
#pragma unroll
            for (int r4 = 0; r4 < 4; ++r4) {
                const float* p = &xs[cc * XCH + (2 * ty + r4) * XSTRIDE + 4 * tx];
                const float4 a  = *(const float4*)p;        // 16B aligned
                const float2 b  = *(const float2*)(p + 4);  //  8B aligned
                xr[r4][0] = a.x; xr[r4][1] = a.y; xr[r4][2] = a.z;
                xr[r4][3] = a.w; xr[r4][4] = b.x; xr[r4][5] = b.y;
            }
#pragma unroll
            for (int f = 0; f < FPB; ++f) {
                const float* wp = &ws[(f * CCHUNK + cc) * WPAD];
                const float4 wa = *(const float4*)wp;        // w0..w3
                const float4 wb = *(const float4*)(wp + 4);  // w4..w7
                const float  w8 = wp[8];
                const float w[9] = {wa.x, wa.y, wa.z, wa.w,
                                    wb.x, wb.y, wb.z, wb.w, w8};
#pragma unroll
                for (int rr = 0; rr < 2; ++rr)
#pragma unroll
                    for (int c = 0; c < 4; ++c) {
                        float s = 0.0f;
#pragma unroll
                        for (int ki = 0; ki < 3; ++ki)
#pragma unroll
                            for (int kj = 0; kj < 3; ++kj)
                                s += fabsf(w[ki * 3 + kj] - xr[rr + ki][c + kj]);
                        acc[rr][c][f] += s;
                    }
            }
        }
        __syncthreads();
    }

    // ---- combine: 32 fp32 atomics per thread ----
#pragma unroll
    for (int f = 0; f < FPB; ++f)
#pragma unroll
        for (int rr = 0; rr < 2; ++rr) {
            const int irow = 2 * ty + rr;
#pragma unroll
            for (int c = 0; c < 4; ++c) {
                const int icol = 4 * tx + c;
                atomicAdd(&out[(((size_t)n * 64 + (f0 + f)) * 32 + irow) * 32 + icol],
                          -acc[rr][c][f]);
            }
        }
}

extern "C" void kernel_launch(void* const* d_in, const int* in_sizes, int n_in,
                              void* d_out, int out_size, void* d_ws, size_t ws_size,
                              hipStream_t stream) {
    const float* x  = (const float*)d_in[0];
    const float* W  = (const float*)d_in[1];
    float* out      = (float*)d_out;
    hipMemsetAsync(d_out, 0, (size_t)out_size * sizeof(float), stream);
    hipLaunchKernelGGL(adder2d_kernel, dim3(1024), dim3(128), 0, stream,
                       x, W, out);
}

// Round 4
// 144.095 us; speedup vs baseline: 1.5258x; 1.5258x over previous
//
#include <hip/hip_runtime.h>

// AdderNet 2D: out[n,f,i,j] = -sum_{c,ki,kj} |W[f,c,ki,kj] - xpad[n,c,i+ki,j+kj]|
// x: [8,64,32,32] f32, W: [64,64,3,3] f32, out: [8,64,32,32] f32
//
// R4: R3's compute loop (8 px x 4 filters/thread, VALU-bound: D=195 vs V/4=288)
// was fine; the scattered fp32 atomics were the disaster (255 MB HBM write-
// through = 64B/lane-atomic). Fix: LDS-transpose the accumulators so the
// combine is lane-contiguous, then either (a) plain float4 partial stores to
// d_ws + tiny reduce kernel (no atomics), or (b) if ws too small, coalesced
// scalar atomics (R2-proven 16-lanes-per-line coalescing).

#define FPB     4
#define CCHUNK  4
#define NCHUNK  2              // channels/block = 8
#define SPLITC  8
#define XSTRIDE 36             // LDS row stride (floats), 16B-aligned
#define XROWS   34             // image rows -1..32
#define XCH     (XROWS * XSTRIDE)   // 1224 floats per channel
#define WPAD    12
#define PXI     1024           // pixels per image plane
#define SLICE_ELEMS (8 * 64 * PXI)            // floats per split slice
#define PART_BYTES  ((size_t)SPLITC * SLICE_ELEMS * 4)   // 16.78 MB

template<int USE_WS>
__global__ __launch_bounds__(128, 2)
void adder2d_kernel(const float* __restrict__ x,
                    const float* __restrict__ Wt,
                    float* __restrict__ out,
                    float* __restrict__ part) {
    __shared__ __align__(16) float xs[CCHUNK * XCH];    // 19584 B
    __shared__ __align__(16) float ws[FPB * CCHUNK * WPAD];

    const int bid = blockIdx.x;
    const int ks  = bid & 7;          // channel slice
    const int fg  = (bid >> 3) & 15;  // filter group
    const int n   = bid >> 7;         // image
    const int f0  = fg * FPB;
    const int tid = threadIdx.x;

    const int tx = tid & 7;           // col group: cols 4tx..4tx+3
    const int ty = tid >> 3;          // row pair:  rows 2ty..2ty+1

    float acc[2][4][FPB];
#pragma unroll
    for (int rr = 0; rr < 2; ++rr)
#pragma unroll
        for (int c = 0; c < 4; ++c)
#pragma unroll
            for (int f = 0; f < FPB; ++f) acc[rr][c][f] = 0.0f;

    const float* xn = x + ((size_t)n * 64 + ks * (CCHUNK * NCHUNK)) * PXI;
    const float* wn = Wt + ((size_t)f0 * 64 + ks * (CCHUNK * NCHUNK)) * 9;

    for (int ch = 0; ch < NCHUNK; ++ch) {
        // ---- stage W chunk: ws[(f*CCHUNK+cc)*12 + k] ----
        for (int idx = tid; idx < FPB * CCHUNK * 9; idx += 128) {
            const int f   = idx / (CCHUNK * 9);
            const int rem = idx - f * (CCHUNK * 9);
            const int cc  = rem / 9;
            const int kk  = rem - cc * 9;
            ws[(f * CCHUNK + cc) * WPAD + kk] =
                wn[((size_t)f * 64 + ch * CCHUNK + cc) * 9 + kk];
        }
        // ---- stage x chunk: rows -1..32 -> 0..33, col -1 -> index 0 ----
        const float* xc = xn + (size_t)ch * CCHUNK * PXI;
        for (int idx = tid; idx < CCHUNK * XCH; idx += 128) {
            const int cc  = idx / XCH;
            const int rem = idx - cc * XCH;
            const int row = rem / XSTRIDE;
            const int col = rem - row * XSTRIDE;
            const int ir  = row - 1;
            const int ic  = col - 1;
            float v = 0.0f;
            if ((unsigned)ir < 32u && (unsigned)ic < 32u)
                v = xc[cc * PXI + ir * 32 + ic];
            xs[idx] = v;
        }
        __syncthreads();

#pragma unroll
        for (int cc = 0; cc < CCHUNK; ++cc) {
            float xr[4][6];
#pragma unroll
            for (int r4 = 0; r4 < 4; ++r4) {
                const float* p = &xs[cc * XCH + (2 * ty + r4) * XSTRIDE + 4 * tx];
                const float4 a = *(const float4*)p;        // 16B aligned
                const float2 b = *(const float2*)(p + 4);  //  8B aligned
                xr[r4][0] = a.x; xr[r4][1] = a.y; xr[r4][2] = a.z;
                xr[r4][3] = a.w; xr[r4][4] = b.x; xr[r4][5] = b.y;
            }
#pragma unroll
            for (int f = 0; f < FPB; ++f) {
                const float* wp = &ws[(f * CCHUNK + cc) * WPAD];
                const float4 wa = *(const float4*)wp;
                const float4 wb = *(const float4*)(wp + 4);
                const float  w8 = wp[8];
                const float w[9] = {wa.x, wa.y, wa.z, wa.w,
                                    wb.x, wb.y, wb.z, wb.w, w8};
#pragma unroll
                for (int rr = 0; rr < 2; ++rr)
#pragma unroll
                    for (int c = 0; c < 4; ++c) {
                        float s = 0.0f;
#pragma unroll
                        for (int ki = 0; ki < 3; ++ki)
#pragma unroll
                            for (int kj = 0; kj < 3; ++kj)
                                s += fabsf(w[ki * 3 + kj] - xr[rr + ki][c + kj]);
                        acc[rr][c][f] += s;
                    }
            }
        }
        __syncthreads();
    }

    // ---- combine: LDS transpose -> lane-contiguous stores/atomics ----
    const size_t obase = ((size_t)n * 64 + f0) * PXI;
#pragma unroll
    for (int f = 0; f < FPB; ++f) {
        __syncthreads();
#pragma unroll
        for (int rr = 0; rr < 2; ++rr)
#pragma unroll
            for (int c = 0; c < 4; ++c)
                xs[(2 * ty + rr) * 32 + 4 * tx + c] = acc[rr][c][f];
        __syncthreads();
        if (USE_WS) {
            float4* dst = (float4*)(part + (size_t)ks * SLICE_ELEMS
                                         + obase + (size_t)f * PXI);
#pragma unroll
            for (int pass = 0; pass < 2; ++pass) {
                const int i4 = pass * 128 + tid;          // 0..255
                dst[i4] = *(const float4*)&xs[i4 * 4];
            }
        } else {
            float* dst = out + obase + (size_t)f * PXI;
#pragma unroll
            for (int pass = 0; pass < 8; ++pass) {
                const int idx = pass * 128 + tid;         // lane-contiguous
                atomicAdd(&dst[idx], -xs[idx]);
            }
        }
    }
}

__global__ __launch_bounds__(256)
void reduce_kernel(const float* __restrict__ part, float* __restrict__ out) {
    const int i4 = blockIdx.x * 256 + threadIdx.x;   // 131072 float4 groups
    const float4* p = (const float4*)part;
    float4 s = p[i4];
#pragma unroll
    for (int sl = 1; sl < SPLITC; ++sl) {
        const float4 v = p[(size_t)sl * (SLICE_ELEMS / 4) + i4];
        s.x += v.x; s.y += v.y; s.z += v.z; s.w += v.w;
    }
    ((float4*)out)[i4] = make_float4(-s.x, -s.y, -s.z, -s.w);
}

extern "C" void kernel_launch(void* const* d_in, const int* in_sizes, int n_in,
                              void* d_out, int out_size, void* d_ws, size_t ws_size,
                              hipStream_t stream) {
    const float* x  = (const float*)d_in[0];
    const float* W  = (const float*)d_in[1];
    float* out      = (float*)d_out;

    if (ws_size >= PART_BYTES) {
        float* part = (float*)d_ws;
        hipLaunchKernelGGL(adder2d_kernel<1>, dim3(1024), dim3(128), 0, stream,
                           x, W, out, part);
        hipLaunchKernelGGL(reduce_kernel, dim3(512), dim3(256), 0, stream,
                           part, out);
    } else {
        hipMemsetAsync(d_out, 0, (size_t)out_size * sizeof(float), stream);
        hipLaunchKernelGGL(adder2d_kernel<0>, dim3(1024), dim3(128), 0, stream,
                           x, W, out, (float*)nullptr);
    }
}